// Round 1
// baseline (613.628 us; speedup 1.0000x reference)
//
#include <hip/hip_runtime.h>
#include <hip/hip_bf16.h>

#define N_NODES 100000
#define N_EDGES 500000
#define LATENT  256
#define HID     256
#define ODIM    128

typedef __attribute__((ext_vector_type(8))) short  short8;   // 8 bf16 = 4 VGPRs (MFMA A/B frag)
typedef __attribute__((ext_vector_type(4))) short  short4v;  // 8B LDS store
typedef __attribute__((ext_vector_type(4))) float  float4v;  // MFMA C/D frag

__device__ __forceinline__ unsigned short f2bf(float f) {
    union { float f; unsigned int u; } v; v.f = f;
    unsigned int u = v.u;
    unsigned int r = u + 0x7fffu + ((u >> 16) & 1u);  // RNE
    return (unsigned short)(r >> 16);
}
__device__ __forceinline__ float bf2f(unsigned short b) {
    union { unsigned int u; float f; } v; v.u = ((unsigned int)b) << 16;
    return v.f;
}

// ---------------- prep: W1 -> W1cat bf16 [512][256], W2 -> bf16 [128][256] --------
__global__ void prep_kernel(const float* __restrict__ W1, const float* __restrict__ W2,
                            unsigned short* __restrict__ w1c, unsigned short* __restrict__ w2b) {
    int j = blockIdx.x, k = threadIdx.x;
    if (j < 512) {
        // W1cat[j][k]: j<256 -> W1[j][k] (src half), else W1[j-256][256+k] (dst half)
        float v = (j < 256) ? W1[(size_t)j * 512 + k] : W1[(size_t)(j - 256) * 512 + 256 + k];
        w1c[(size_t)j * 256 + k] = f2bf(v);
    } else {
        int o = j - 512;
        w2b[(size_t)o * 256 + k] = f2bf(W2[(size_t)o * 256 + k]);
    }
}

// ---------------- stage 1: ZW[N,512](bf16) = z[N,256](f32) @ W1cat^T ----------------
// 128x128 tile, BK=32, 4 waves in 2x2, each wave 4x4 tiles of 16x16x32 bf16 MFMA.
#define S1_PITCH 40   // 32 + 8 bf16 pad -> 80B row pitch (16B aligned, 2-way banks: free)
__launch_bounds__(256, 2)
__global__ void stage1_kernel(const float* __restrict__ z, const unsigned short* __restrict__ w1c,
                              unsigned short* __restrict__ ZW) {
    __shared__ unsigned short lds[128 * 136];          // 34816B; staging tiles alias front
    unsigned short* At = lds;                          // 128 x S1_PITCH
    unsigned short* Bt = lds + 128 * S1_PITCH;         // 128 x S1_PITCH

    const int t    = threadIdx.x;
    const int lane = t & 63, wave = t >> 6;
    const int wm = wave >> 1, wn = wave & 1;
    const int l15 = lane & 15, quad = lane >> 4;
    const int mbase = blockIdx.x * 128;
    const int nbase = blockIdx.y * 128;

    // staging mapping: 2 threads per row
    const int sr = t >> 1, sp = t & 1;
    int arow = mbase + sr; if (arow >= N_NODES) arow = N_NODES - 1;
    const float*          aptr = z   + (size_t)arow * 256;
    const unsigned short* bptr = w1c + (size_t)(nbase + sr) * 256;

    float4v acc[4][4];
    const float4v fz = {0.f, 0.f, 0.f, 0.f};
#pragma unroll
    for (int i = 0; i < 4; ++i)
#pragma unroll
        for (int j = 0; j < 4; ++j) acc[i][j] = fz;

    for (int kk = 0; kk < 256; kk += 32) {
        __syncthreads();
        // stage A: 16 f32 per thread -> bf16 LDS
        {
            const float4v* src = (const float4v*)(aptr + kk + sp * 16);
            short4v* dst = (short4v*)(At + sr * S1_PITCH + sp * 16);
#pragma unroll
            for (int i = 0; i < 4; ++i) {
                float4v v = src[i];
                short4v s;
                s.x = (short)f2bf(v.x); s.y = (short)f2bf(v.y);
                s.z = (short)f2bf(v.z); s.w = (short)f2bf(v.w);
                dst[i] = s;
            }
        }
        // stage B: 16 bf16 per thread (already bf16)
        {
            const short8* src = (const short8*)(bptr + kk + sp * 16);
            *(short8*)(Bt + sr * S1_PITCH + sp * 16)     = src[0];
            *(short8*)(Bt + sr * S1_PITCH + sp * 16 + 8) = src[1];
        }
        __syncthreads();

        short8 af[4], bf[4];
#pragma unroll
        for (int i = 0; i < 4; ++i)
            af[i] = *(const short8*)(At + (wm * 64 + i * 16 + l15) * S1_PITCH + quad * 8);
#pragma unroll
        for (int j = 0; j < 4; ++j)
            bf[j] = *(const short8*)(Bt + (wn * 64 + j * 16 + l15) * S1_PITCH + quad * 8);
#pragma unroll
        for (int i = 0; i < 4; ++i)
#pragma unroll
            for (int j = 0; j < 4; ++j)
                acc[i][j] = __builtin_amdgcn_mfma_f32_16x16x32_bf16(af[i], bf[j], acc[i][j], 0, 0, 0);
    }

    // epilogue: acc (C layout: row=quad*4+r, col=l15) -> LDS bf16 -> coalesced global
    __syncthreads();
#pragma unroll
    for (int i = 0; i < 4; ++i)
#pragma unroll
        for (int j = 0; j < 4; ++j) {
            int row = wm * 64 + i * 16 + quad * 4;
            int col = wn * 64 + j * 16 + l15;
#pragma unroll
            for (int r = 0; r < 4; ++r)
                lds[(row + r) * 136 + col] = f2bf(acc[i][j][r]);
        }
    __syncthreads();
    for (int c = t; c < 128 * 16; c += 256) {
        int row = c >> 4, ch = c & 15;
        int grow = mbase + row;
        if (grow < N_NODES)
            *(short8*)(ZW + (size_t)grow * 512 + nbase + ch * 8) =
                *(const short8*)(lds + row * 136 + ch * 8);
    }
}

// ---------------- stage 2: per 128-edge tile: gather+ReLU -> h bf16 LDS; out = h @ W2^T + b2
#define H_PITCH 264   // 256 + 8 pad
__launch_bounds__(256, 2)
__global__ void stage2_kernel(const int* __restrict__ eidx, const unsigned short* __restrict__ ZW,
                              const float* __restrict__ b1, const unsigned short* __restrict__ w2b,
                              const float* __restrict__ b2, float* __restrict__ out) {
    __shared__ unsigned short h[128 * H_PITCH];  // 67584 B -> 2 blocks/CU
    const int t  = threadIdx.x;
    const int eb = blockIdx.x * 128;

    // ---- gather phase: 32 lanes per edge-row, 8 edges per pass, 16 passes
    const int lj = t & 31;   // 8-col chunk
    const int er = t >> 5;   // 0..7
    float4v b1a = *(const float4v*)(b1 + lj * 8);
    float4v b1b = *(const float4v*)(b1 + lj * 8 + 4);
    for (int p = 0; p < 16; ++p) {
        int el = p * 8 + er;
        int e  = eb + el;
        int ec = e < N_EDGES ? e : N_EDGES - 1;
        int s = eidx[ec], d = eidx[N_EDGES + ec];
        short8 va = *(const short8*)(ZW + (size_t)s * 512 + lj * 8);         // Za[src]
        short8 vb = *(const short8*)(ZW + (size_t)d * 512 + 256 + lj * 8);   // Zb[dst]
        short8 rv;
#pragma unroll
        for (int i = 0; i < 8; ++i) {
            float fa = bf2f((unsigned short)va[i]);
            float fb = bf2f((unsigned short)vb[i]);
            float bias = (i < 4) ? b1a[i] : b1b[i - 4];
            float v = fa + fb + bias;
            v = v > 0.f ? v : 0.f;
            rv[i] = (short)f2bf(v);
        }
        *(short8*)(h + el * H_PITCH + lj * 8) = rv;
    }
    __syncthreads();

    // ---- MFMA phase: 128x128 out tile, K=256; W2 frags straight from global (L1-resident 64KB)
    const int lane = t & 63, wave = t >> 6;
    const int wm = wave >> 1, wn = wave & 1;
    const int l15 = lane & 15, quad = lane >> 4;
    float4v acc[4][4];
    const float4v fz = {0.f, 0.f, 0.f, 0.f};
#pragma unroll
    for (int i = 0; i < 4; ++i)
#pragma unroll
        for (int j = 0; j < 4; ++j) acc[i][j] = fz;

    const unsigned short* wptr[4];
#pragma unroll
    for (int j = 0; j < 4; ++j)
        wptr[j] = w2b + (size_t)(wn * 64 + j * 16 + l15) * 256 + quad * 8;

    for (int kk = 0; kk < 256; kk += 32) {
        short8 af[4], bfr[4];
#pragma unroll
        for (int i = 0; i < 4; ++i)
            af[i] = *(const short8*)(h + (wm * 64 + i * 16 + l15) * H_PITCH + kk + quad * 8);
#pragma unroll
        for (int j = 0; j < 4; ++j)
            bfr[j] = *(const short8*)(wptr[j] + kk);
#pragma unroll
        for (int i = 0; i < 4; ++i)
#pragma unroll
            for (int j = 0; j < 4; ++j)
                acc[i][j] = __builtin_amdgcn_mfma_f32_16x16x32_bf16(af[i], bfr[j], acc[i][j], 0, 0, 0);
    }

    // ---- epilogue: + b2, fp32 store (16 lanes x 4B contiguous per quad)
#pragma unroll
    for (int j = 0; j < 4; ++j) {
        int col = wn * 64 + j * 16 + l15;
        float bias = b2[col];
#pragma unroll
        for (int i = 0; i < 4; ++i) {
            int row0 = wm * 64 + i * 16 + quad * 4;
#pragma unroll
            for (int r = 0; r < 4; ++r) {
                int e = eb + row0 + r;
                if (e < N_EDGES) out[(size_t)e * 128 + col] = acc[i][j][r] + bias;
            }
        }
    }
}

// ---------------- fallback (ws too small): exact fp32, 1 block per edge ----------------
__global__ void fallback_kernel(const float* __restrict__ z, const int* __restrict__ eidx,
                                const float* __restrict__ W1, const float* __restrict__ b1,
                                const float* __restrict__ W2, const float* __restrict__ b2,
                                float* __restrict__ out) {
    __shared__ float zs[512];
    __shared__ float hh[256];
    int e = blockIdx.x, t = threadIdx.x;
    int s = eidx[e], d = eidx[N_EDGES + e];
    zs[t]       = z[(size_t)s * 256 + t];
    zs[256 + t] = z[(size_t)d * 256 + t];
    __syncthreads();
    float a = b1[t];
    const float* wr = W1 + (size_t)t * 512;
    for (int k = 0; k < 512; ++k) a += zs[k] * wr[k];
    hh[t] = a > 0.f ? a : 0.f;
    __syncthreads();
    if (t < 128) {
        float o = b2[t];
        const float* w2r = W2 + (size_t)t * 256;
        for (int k = 0; k < 256; ++k) o += hh[k] * w2r[k];
        out[(size_t)e * 128 + t] = o;
    }
}

extern "C" void kernel_launch(void* const* d_in, const int* in_sizes, int n_in,
                              void* d_out, int out_size, void* d_ws, size_t ws_size,
                              hipStream_t stream) {
    const float* z    = (const float*)d_in[0];
    const int*   eidx = (const int*)d_in[1];
    const float* W1   = (const float*)d_in[2];
    const float* b1   = (const float*)d_in[3];
    const float* W2   = (const float*)d_in[4];
    const float* b2   = (const float*)d_in[5];
    float* out = (float*)d_out;

    const size_t zw_bytes = (size_t)N_NODES * 512 * 2;   // 102,400,000
    const size_t w1c_off  = zw_bytes;
    const size_t w2b_off  = w1c_off + (size_t)512 * 256 * 2;
    const size_t need     = w2b_off + (size_t)128 * 256 * 2;

    if (ws_size < need) {
        fallback_kernel<<<N_EDGES, 256, 0, stream>>>(z, eidx, W1, b1, W2, b2, out);
        return;
    }
    unsigned short* ZW  = (unsigned short*)d_ws;
    unsigned short* w1c = (unsigned short*)((char*)d_ws + w1c_off);
    unsigned short* w2b = (unsigned short*)((char*)d_ws + w2b_off);

    prep_kernel<<<640, 256, 0, stream>>>(W1, W2, w1c, w2b);
    stage1_kernel<<<dim3(782, 4), 256, 0, stream>>>(z, w1c, ZW);     // ceil(100000/128)=782
    stage2_kernel<<<3907, 256, 0, stream>>>(eidx, ZW, b1, w2b, b2, out); // ceil(500000/128)=3907
}

// Round 2
// 545.222 us; speedup vs baseline: 1.1255x; 1.1255x over previous
//
#include <hip/hip_runtime.h>
#include <hip/hip_bf16.h>

#define N_NODES 100000
#define N_EDGES 500000

typedef __attribute__((ext_vector_type(8))) short  short8;   // 8 bf16 (4 VGPRs)
typedef __attribute__((ext_vector_type(4))) short  short4v;
typedef __attribute__((ext_vector_type(4))) float  float4v;

__device__ __forceinline__ unsigned short f2bf(float f) {
    union { float f; unsigned int u; } v; v.f = f;
    unsigned int u = v.u;
    unsigned int r = u + 0x7fffu + ((u >> 16) & 1u);  // RNE
    return (unsigned short)(r >> 16);
}
__device__ __forceinline__ float bf2f(unsigned short b) {
    union { unsigned int u; float f; } v; v.u = ((unsigned int)b) << 16;
    return v.f;
}

// async global->LDS, 16B per lane; lptr must follow wave-uniform-base + lane*16 order
__device__ __forceinline__ void gload_lds16(const unsigned short* g, unsigned short* l) {
    __builtin_amdgcn_global_load_lds(
        (const __attribute__((address_space(1))) unsigned int*)g,
        (__attribute__((address_space(3))) unsigned int*)l, 16, 0, 0);
}

// ---------------- z -> bf16 (zb lives in d_out's first 51.2MB; consumed before stage2 writes)
__global__ void zconv_kernel(const float* __restrict__ z, unsigned short* __restrict__ zb) {
    size_t i = ((size_t)blockIdx.x * 256 + threadIdx.x) * 8;   // 12500*256*8 = 25,600,000 exact
    float4v a = *(const float4v*)(z + i);
    float4v b = *(const float4v*)(z + i + 4);
    short8 o;
    o[0] = (short)f2bf(a.x); o[1] = (short)f2bf(a.y); o[2] = (short)f2bf(a.z); o[3] = (short)f2bf(a.w);
    o[4] = (short)f2bf(b.x); o[5] = (short)f2bf(b.y); o[6] = (short)f2bf(b.z); o[7] = (short)f2bf(b.w);
    *(short8*)(zb + i) = o;
}

// ---------------- prep: W1 -> W1cat bf16 [512][256], W2 -> bf16 [128][256]
__global__ void prep_kernel(const float* __restrict__ W1, const float* __restrict__ W2,
                            unsigned short* __restrict__ w1c, unsigned short* __restrict__ w2b) {
    int j = blockIdx.x, k = threadIdx.x;
    if (j < 512) {
        float v = (j < 256) ? W1[(size_t)j * 512 + k] : W1[(size_t)(j - 256) * 512 + 256 + k];
        w1c[(size_t)j * 256 + k] = f2bf(v);
    } else {
        int o = j - 512;
        w2b[(size_t)o * 256 + k] = f2bf(W2[(size_t)o * 256 + k]);
    }
}

// ---------------- stage 1: ZW[N,512](bf16) = zb[N,256] @ w1c^T, m97-style staging ----------
// LDS A/B tiles 128x64 bf16, unpadded, XOR-swizzled in 16B chunks: LDS[row][c] = G[row][c^(row&7)]
__launch_bounds__(256, 2)
__global__ void stage1_kernel(const unsigned short* __restrict__ zb,
                              const unsigned short* __restrict__ w1c,
                              unsigned short* __restrict__ ZW) {
    __shared__ unsigned short lds[128 * 136];       // 34816B; staging uses first 32KB
    unsigned short* At = lds;                       // [128][64]
    unsigned short* Bt = lds + 128 * 64;

    const int t    = threadIdx.x;
    const int lane = t & 63, wave = t >> 6;
    const int wm = wave >> 1, wn = wave & 1;
    const int l15 = lane & 15, quad = lane >> 4;
    const int mbase = blockIdx.x * 128, nbase = blockIdx.y * 128;

    // staging: inst (wave,q) covers rows wave*32+q*8 .. +8; lane lr=lane>>3 row, swizzled chunk
    const int lr = lane >> 3;
    const int cg = (lane & 7) ^ lr;                  // source chunk so LDS gets xor layout
    const unsigned short* ag[4]; const unsigned short* bg[4];
    unsigned short* al[4]; unsigned short* bl[4];
#pragma unroll
    for (int q = 0; q < 4; ++q) {
        int rA = wave * 32 + q * 8 + lr;
        int gA = mbase + rA; if (gA >= N_NODES) gA = N_NODES - 1;
        ag[q] = zb  + (size_t)gA * 256 + cg * 8;
        bg[q] = w1c + (size_t)(nbase + rA) * 256 + cg * 8;
        al[q] = At + (wave * 4 + q) * 512 + lane * 8;   // linear: base + lane*16B
        bl[q] = Bt + (wave * 4 + q) * 512 + lane * 8;
    }

    float4v acc[4][4];
    const float4v fz = {0.f, 0.f, 0.f, 0.f};
#pragma unroll
    for (int i = 0; i < 4; ++i)
#pragma unroll
        for (int j = 0; j < 4; ++j) acc[i][j] = fz;

    for (int kk = 0; kk < 256; kk += 64) {
        __syncthreads();
#pragma unroll
        for (int q = 0; q < 4; ++q) gload_lds16(ag[q] + kk, al[q]);
#pragma unroll
        for (int q = 0; q < 4; ++q) gload_lds16(bg[q] + kk, bl[q]);
        __syncthreads();   // drains vmcnt (global_load_lds) + lgkm

#pragma unroll
        for (int s = 0; s < 2; ++s) {
            const int ch = ((s * 4 + quad) ^ (l15 & 7)) * 8;   // de-swizzle (row&7 == l15&7)
            short8 af[4], bfr[4];
#pragma unroll
            for (int i = 0; i < 4; ++i)
                af[i] = *(const short8*)(At + (wm * 64 + i * 16 + l15) * 64 + ch);
#pragma unroll
            for (int j = 0; j < 4; ++j)
                bfr[j] = *(const short8*)(Bt + (wn * 64 + j * 16 + l15) * 64 + ch);
#pragma unroll
            for (int i = 0; i < 4; ++i)
#pragma unroll
                for (int j = 0; j < 4; ++j)
                    acc[i][j] = __builtin_amdgcn_mfma_f32_16x16x32_bf16(af[i], bfr[j], acc[i][j], 0, 0, 0);
        }
    }

    // epilogue: acc (row=quad*4+r, col=l15) -> LDS bf16 -> coalesced short8 stores
    __syncthreads();
#pragma unroll
    for (int i = 0; i < 4; ++i)
#pragma unroll
        for (int j = 0; j < 4; ++j) {
            int row = wm * 64 + i * 16 + quad * 4;
            int col = wn * 64 + j * 16 + l15;
#pragma unroll
            for (int r = 0; r < 4; ++r)
                lds[(row + r) * 136 + col] = f2bf(acc[i][j][r]);
        }
    __syncthreads();
    for (int c = t; c < 128 * 16; c += 256) {
        int row = c >> 4, ch2 = c & 15;
        int grow = mbase + row;
        if (grow < N_NODES)
            *(short8*)(ZW + (size_t)grow * 512 + nbase + ch2 * 8) =
                *(const short8*)(lds + row * 136 + ch2 * 8);
    }
}

// ---------------- stage 2: gather+bias+ReLU -> h (LDS bf16); out = h @ W2^T + b2 ------------
#define H_PITCH 264
__launch_bounds__(256, 2)
__global__ void stage2_kernel(const int* __restrict__ eidx, const unsigned short* __restrict__ ZW,
                              const float* __restrict__ b1, const unsigned short* __restrict__ w2b,
                              const float* __restrict__ b2, float* __restrict__ out) {
    __shared__ unsigned short h[128 * H_PITCH];   // 67584 B
    __shared__ int idx[256];                      // src[0..127], dst[128..255]
    const int t    = threadIdx.x;
    const int lane = t & 63, wave = t >> 6;
    const int l15 = lane & 15, quad = lane >> 4;
    const int wm = wave >> 1, wn = wave & 1;
    const int eb = blockIdx.x * 128;

    {   // edge indices -> LDS (kills the per-pass idx->gather dependent chain)
        int e = eb + (t & 127); if (e >= N_EDGES) e = N_EDGES - 1;
        idx[t] = eidx[(t >> 7) * N_EDGES + e];
    }

    // W2 fragments kk=0..3 preloaded into regs (issued now, consumed after the gather phase)
    const unsigned short* wr[4];
#pragma unroll
    for (int j = 0; j < 4; ++j)
        wr[j] = w2b + (size_t)(wn * 64 + j * 16 + l15) * 256 + quad * 8;
    short8 bfrag[4][4];
#pragma unroll
    for (int kk = 0; kk < 4; ++kk)
#pragma unroll
        for (int j = 0; j < 4; ++j)
            bfrag[j][kk] = *(const short8*)(wr[j] + kk * 32);

    __syncthreads();

    // ---- gather: 32 lanes x 16B per edge-row, depth-4 software pipeline
    const int lj = t & 31, er = t >> 5;
    float4v b1a = *(const float4v*)(b1 + lj * 8);
    float4v b1b = *(const float4v*)(b1 + lj * 8 + 4);
    const unsigned short* zs = ZW + lj * 8;
    const unsigned short* zd = ZW + 256 + lj * 8;

    short8 va[4], vb[4];
#pragma unroll
    for (int p = 0; p < 4; ++p) {
        int el = p * 8 + er;
        va[p] = *(const short8*)(zs + (size_t)idx[el] * 512);
        vb[p] = *(const short8*)(zd + (size_t)idx[128 + el] * 512);
    }
#pragma unroll
    for (int p = 0; p < 16; ++p) {
        int el = p * 8 + er;
        short8 xa = va[p & 3], xb = vb[p & 3];
        if (p < 12) {
            int el4 = el + 32;
            va[p & 3] = *(const short8*)(zs + (size_t)idx[el4] * 512);
            vb[p & 3] = *(const short8*)(zd + (size_t)idx[128 + el4] * 512);
        }
        short8 rv;
#pragma unroll
        for (int i = 0; i < 8; ++i) {
            float v = bf2f((unsigned short)xa[i]) + bf2f((unsigned short)xb[i])
                    + ((i < 4) ? b1a[i] : b1b[i - 4]);
            v = v > 0.f ? v : 0.f;
            rv[i] = (short)f2bf(v);
        }
        *(short8*)(h + el * H_PITCH + lj * 8) = rv;
    }
    __syncthreads();

    // ---- MFMA: A from h (LDS), B from regs (kk<4) / distance-1 prefetch (kk>=4)
    float4v acc[4][4];
    const float4v fz = {0.f, 0.f, 0.f, 0.f};
#pragma unroll
    for (int i = 0; i < 4; ++i)
#pragma unroll
        for (int j = 0; j < 4; ++j) acc[i][j] = fz;

    short8 pre[4];
#pragma unroll
    for (int j = 0; j < 4; ++j) pre[j] = *(const short8*)(wr[j] + 4 * 32);

#pragma unroll
    for (int kk = 0; kk < 8; ++kk) {
        short8 af[4];
#pragma unroll
        for (int i = 0; i < 4; ++i)
            af[i] = *(const short8*)(h + (wm * 64 + i * 16 + l15) * H_PITCH + kk * 32 + quad * 8);
        short8 bcur[4];
        if (kk < 4) {
#pragma unroll
            for (int j = 0; j < 4; ++j) bcur[j] = bfrag[j][kk];
        } else {
#pragma unroll
            for (int j = 0; j < 4; ++j) bcur[j] = pre[j];
            if (kk < 7) {
#pragma unroll
                for (int j = 0; j < 4; ++j) pre[j] = *(const short8*)(wr[j] + (kk + 1) * 32);
            }
        }
#pragma unroll
        for (int i = 0; i < 4; ++i)
#pragma unroll
            for (int j = 0; j < 4; ++j)
                acc[i][j] = __builtin_amdgcn_mfma_f32_16x16x32_bf16(af[i], bcur[j], acc[i][j], 0, 0, 0);
    }

    // ---- epilogue: + b2, fp32 stores
#pragma unroll
    for (int j = 0; j < 4; ++j) {
        int col = wn * 64 + j * 16 + l15;
        float bias = b2[col];
#pragma unroll
        for (int i = 0; i < 4; ++i) {
            int row0 = wm * 64 + i * 16 + quad * 4;
#pragma unroll
            for (int r = 0; r < 4; ++r) {
                int e = eb + row0 + r;
                if (e < N_EDGES) out[(size_t)e * 128 + col] = acc[i][j][r] + bias;
            }
        }
    }
}

// ---------------- fallback (ws too small): exact fp32 ----------------
__global__ void fallback_kernel(const float* __restrict__ z, const int* __restrict__ eidx,
                                const float* __restrict__ W1, const float* __restrict__ b1,
                                const float* __restrict__ W2, const float* __restrict__ b2,
                                float* __restrict__ out) {
    __shared__ float zs[512];
    __shared__ float hh[256];
    int e = blockIdx.x, t = threadIdx.x;
    int s = eidx[e], d = eidx[N_EDGES + e];
    zs[t]       = z[(size_t)s * 256 + t];
    zs[256 + t] = z[(size_t)d * 256 + t];
    __syncthreads();
    float a = b1[t];
    const float* wr = W1 + (size_t)t * 512;
    for (int k = 0; k < 512; ++k) a += zs[k] * wr[k];
    hh[t] = a > 0.f ? a : 0.f;
    __syncthreads();
    if (t < 128) {
        float o = b2[t];
        const float* w2r = W2 + (size_t)t * 256;
        for (int k = 0; k < 256; ++k) o += hh[k] * w2r[k];
        out[(size_t)e * 128 + t] = o;
    }
}

extern "C" void kernel_launch(void* const* d_in, const int* in_sizes, int n_in,
                              void* d_out, int out_size, void* d_ws, size_t ws_size,
                              hipStream_t stream) {
    const float* z    = (const float*)d_in[0];
    const int*   eidx = (const int*)d_in[1];
    const float* W1   = (const float*)d_in[2];
    const float* b1   = (const float*)d_in[3];
    const float* W2   = (const float*)d_in[4];
    const float* b2   = (const float*)d_in[5];
    float* out = (float*)d_out;

    const size_t zw_bytes = (size_t)N_NODES * 512 * 2;          // 102,400,000
    const size_t w1c_off  = zw_bytes;
    const size_t w2b_off  = w1c_off + (size_t)512 * 256 * 2;
    const size_t need     = w2b_off + (size_t)128 * 256 * 2;

    if (ws_size < need) {
        fallback_kernel<<<N_EDGES, 256, 0, stream>>>(z, eidx, W1, b1, W2, b2, out);
        return;
    }
    unsigned short* ZW  = (unsigned short*)d_ws;
    unsigned short* w1c = (unsigned short*)((char*)d_ws + w1c_off);
    unsigned short* w2b = (unsigned short*)((char*)d_ws + w2b_off);
    // zb scratch lives in d_out (51.2MB of 256MB); consumed by stage1 before stage2 writes out
    unsigned short* zb  = (unsigned short*)d_out;

    zconv_kernel<<<12500, 256, 0, stream>>>(z, zb);
    prep_kernel<<<640, 256, 0, stream>>>(W1, W2, w1c, w2b);
    stage1_kernel<<<dim3(782, 4), 256, 0, stream>>>(zb, w1c, ZW);
    stage2_kernel<<<3907, 256, 0, stream>>>(eidx, ZW, b1, w2b, b2, out);
}